// Round 6
// baseline (86.379 us; speedup 1.0000x reference)
//
#include <hip/hip_runtime.h>
#include <math.h>

#define NB 32
#define NT 512
#define NS 64
#define NOBS 4
#define NEMB 32
#define NPE 16
#define NATTN 10
#define ND 26  // ATTN + PE

// obs_emb_weights LDS layout: 64 rows (sensor s) x 128 dwords (o*32+e),
// 16B-chunk XOR swizzle so per-lane ds_read_b128 of row s spreads banks.
__device__ __forceinline__ int obs_idx(int s, int chunk) {
    return (s << 7) + (((chunk ^ (s & 7)) & 31) << 2);
}

// wave-wide broadcast of lane l's value via v_readlane (VALU->SGPR, no LDS)
__device__ __forceinline__ float readlane_f32(float v, int l) {
    int vi = __builtin_bit_cast(int, v);
    int r = __builtin_amdgcn_readlane(vi, l);
    return __builtin_bit_cast(float, r);
}

__global__ __launch_bounds__(512)
void raindrop_kernel(const float* __restrict__ x,
                     const float* __restrict__ times,
                     const float* __restrict__ mask,
                     const float* __restrict__ obsW,
                     const float* __restrict__ attnW,
                     const float* __restrict__ recvW,
                     const float* __restrict__ recvB,
                     float* __restrict__ out)
{
    // 32 KiB swizzled obsW tile (phase 1 only; no reuse needed anymore)
    __shared__ float lds[NS * 128];
    // per-wave folded PE weights: w_pe[e] = sum_p recvW[e][10+p]*pe[p]
    __shared__ float wpe[8 * NEMB];  // 1 KiB

    const int tid = threadIdx.x;

    // Stage S*OBS*EMB = 8192 floats into LDS (coalesced global float4 reads,
    // swizzled LDS writes). 512 threads x 4 iters x 4 floats.
#pragma unroll
    for (int k = 0; k < 4; ++k) {
        int i = (tid << 2) + (k << 11);
        float4 v = *reinterpret_cast<const float4*>(obsW + i);
        *reinterpret_cast<float4*>(&lds[obs_idx(i >> 7, (i & 127) >> 2)]) = v;
    }

    const int lane = tid & 63;
    const int wv = tid >> 6;
    const int bt = blockIdx.x * 8 + wv;   // one wave per (b,t)
    const int s = lane;                   // phase-1 role: lane = sensor

    // per-lane attnW row for phase-3 role u = lane (10 VGPRs, loaded once)
    float aW[NATTN];
    {
        const float2* ap = reinterpret_cast<const float2*>(attnW + lane * NATTN);
        float2 a0 = ap[0], a1 = ap[1], a2 = ap[2], a3 = ap[3], a4 = ap[4];
        aW[0] = a0.x; aW[1] = a0.y; aW[2] = a1.x; aW[3] = a1.y; aW[4] = a2.x;
        aW[5] = a2.y; aW[6] = a3.x; aW[7] = a3.y; aW[8] = a4.x; aW[9] = a4.y;
    }

    // positional encoding (wave-uniform; div[i] = 10^(-i/2)); native sin/cos
    const float tt = times[bt];
    const float divs[8] = {1.0f, 0.31622776601683794f, 0.1f, 0.031622776601683794f,
                           0.01f, 0.0031622776601683794f, 0.001f, 0.00031622776601683794f};
    float pe[NPE];
#pragma unroll
    for (int i = 0; i < 8; ++i) {
        float ang = tt * divs[i];
        pe[2 * i]     = __sinf(ang);
        pe[2 * i + 1] = __cosf(ang);
    }

    // c0 = recvB[10:26] . pe  (uniform; recvB via s_load)
    float c0 = 0.f;
#pragma unroll
    for (int p = 0; p < NPE; ++p) c0 += recvB[NATTN + p] * pe[p];

    // w_pe: lane e (= lane&31) folds recvW[e][10..25] with pe -> LDS strip.
    {
        const int e = lane & 31;
        const float2* rp = reinterpret_cast<const float2*>(recvW + e * ND + NATTN);
        float acc = 0.f;
#pragma unroll
        for (int p2 = 0; p2 < 8; ++p2) {
            float2 w = rp[p2];
            acc += w.x * pe[2 * p2];
            acc += w.y * pe[2 * p2 + 1];
        }
        if (lane < NEMB) wpe[wv * NEMB + e] = acc;
    }

    // per-lane inputs (coalesced: 64 lanes x 16B contiguous)
    const float4 xv = *reinterpret_cast<const float4*>(x + ((size_t)bt * NS + s) * NOBS);
    const float  mv = mask[(size_t)bt * NS + s];

    __syncthreads();  // obsW tile + wpe ready (the ONLY barrier)

    // hq[a] = recv_b[a] + sum_e h_e * recv_W[e][a]   (a = 0..9 only)
    // beta' = sum_e h_e * w_pe[e]
    float hq[NATTN];
#pragma unroll
    for (int a = 0; a < NATTN; ++a) hq[a] = recvB[a];  // uniform -> s_load
    float betah = 0.f;

    const float* wpb = &wpe[wv * NEMB];

#pragma unroll
    for (int eb = 0; eb < 8; ++eb) {  // e = eb*4 + j
        float a0 = 0.f, a1 = 0.f, a2 = 0.f, a3 = 0.f;
        {
            float4 w0 = *reinterpret_cast<const float4*>(&lds[obs_idx(s, 0 * 8 + eb)]);
            a0 += xv.x * w0.x; a1 += xv.x * w0.y; a2 += xv.x * w0.z; a3 += xv.x * w0.w;
            float4 w1 = *reinterpret_cast<const float4*>(&lds[obs_idx(s, 1 * 8 + eb)]);
            a0 += xv.y * w1.x; a1 += xv.y * w1.y; a2 += xv.y * w1.z; a3 += xv.y * w1.w;
            float4 w2 = *reinterpret_cast<const float4*>(&lds[obs_idx(s, 2 * 8 + eb)]);
            a0 += xv.z * w2.x; a1 += xv.z * w2.y; a2 += xv.z * w2.z; a3 += xv.z * w2.w;
            float4 w3 = *reinterpret_cast<const float4*>(&lds[obs_idx(s, 3 * 8 + eb)]);
            a0 += xv.w * w3.x; a1 += xv.w * w3.y; a2 += xv.w * w3.z; a3 += xv.w * w3.w;
        }
        const float h0 = fmaxf(a0, 0.f) * mv;
        const float h1 = fmaxf(a1, 0.f) * mv;
        const float h2 = fmaxf(a2, 0.f) * mv;
        const float h3 = fmaxf(a3, 0.f) * mv;

        // beta' contribution: uniform ds_read_b128 broadcast of 4 w_pe values
        float4 wp = *reinterpret_cast<const float4*>(wpb + eb * 4);
        betah += h0 * wp.x + h1 * wp.y + h2 * wp.z + h3 * wp.w;

        const float* rw = recvW + (eb * 4) * ND;  // uniform base -> s_load
#pragma unroll
        for (int a = 0; a < NATTN; ++a) {
            hq[a] += h0 * rw[a] + h1 * rw[ND + a] + h2 * rw[2 * ND + a] + h3 * rw[3 * ND + a];
        }
    }

    const float beta = c0 + betah;

    // Phase 3: lane = u. Row r's (hq,beta) live in lane r's VGPRs (same wave)
    // -> broadcast via v_readlane (VALU->SGPR), ZERO LDS traffic, no barrier.
    // Per row: 11 readlane + 10 FMA (SGPR operand) + relu + coalesced 256B store.
    float* obase = out + (size_t)bt * (NS * NS) + lane;
#pragma unroll 8
    for (int r = 0; r < NS; ++r) {
        float b_r = readlane_f32(beta, r);
        float q0 = readlane_f32(hq[0], r);
        float q1 = readlane_f32(hq[1], r);
        float q2 = readlane_f32(hq[2], r);
        float q3 = readlane_f32(hq[3], r);
        float q4 = readlane_f32(hq[4], r);
        float q5 = readlane_f32(hq[5], r);
        float q6 = readlane_f32(hq[6], r);
        float q7 = readlane_f32(hq[7], r);
        float q8 = readlane_f32(hq[8], r);
        float q9 = readlane_f32(hq[9], r);
        float acc = b_r;
        acc += q0 * aW[0]; acc += q1 * aW[1];
        acc += q2 * aW[2]; acc += q3 * aW[3];
        acc += q4 * aW[4]; acc += q5 * aW[5];
        acc += q6 * aW[6]; acc += q7 * aW[7];
        acc += q8 * aW[8]; acc += q9 * aW[9];
        obase[r * NS] = fmaxf(acc, 0.f);  // 64 lanes x 4B contiguous
    }
}

extern "C" void kernel_launch(void* const* d_in, const int* in_sizes, int n_in,
                              void* d_out, int out_size, void* d_ws, size_t ws_size,
                              hipStream_t stream) {
    const float* x     = (const float*)d_in[0];
    const float* times = (const float*)d_in[1];
    const float* mask  = (const float*)d_in[2];
    const float* obsW  = (const float*)d_in[3];
    const float* attnW = (const float*)d_in[4];
    const float* recvW = (const float*)d_in[5];
    const float* recvB = (const float*)d_in[6];
    float* out = (float*)d_out;

    // B*T = 16384 (b,t) pairs, one wave each, 8 waves per block
    raindrop_kernel<<<dim3((NB * NT) / 8), dim3(512), 0, stream>>>(
        x, times, mask, obsW, attnW, recvW, recvB, out);
}

// Round 7
// 83.451 us; speedup vs baseline: 1.0351x; 1.0351x over previous
//
#include <hip/hip_runtime.h>
#include <math.h>

#define NB 32
#define NT 512
#define NS 64
#define NOBS 4
#define NEMB 32
#define NPE 16
#define NATTN 10
#define ND 26  // ATTN + PE

// obs_emb_weights LDS layout: 64 rows (sensor s) x 128 dwords (o*32+e),
// 16B-chunk XOR swizzle so per-lane ds_read_b128 of row s spreads banks.
__device__ __forceinline__ int obs_idx(int s, int chunk) {
    return (s << 7) + (((chunk ^ (s & 7)) & 31) << 2);
}

// pack two f32 -> one dword of two f16 (scalar cvt path; NO half ext-vectors)
__device__ __forceinline__ unsigned pkh(float a, float b) {
    _Float16 ha = (_Float16)a, hb = (_Float16)b;
    unsigned short ua, ub;
    __builtin_memcpy(&ua, &ha, 2);
    __builtin_memcpy(&ub, &hb, 2);
    return (unsigned)ua | ((unsigned)ub << 16);
}

// unpack dword of two f16 -> float2 (proven R4-kernel-B pattern)
__device__ __forceinline__ float2 unpack_h2(unsigned u) {
    unsigned short l16 = (unsigned short)(u & 0xffffu);
    unsigned short h16 = (unsigned short)(u >> 16);
    _Float16 lo, hi;
    __builtin_memcpy(&lo, &l16, 2);
    __builtin_memcpy(&hi, &h16, 2);
    return make_float2((float)lo, (float)hi);
}

__global__ __launch_bounds__(512)
void raindrop_kernel(const float* __restrict__ x,
                     const float* __restrict__ times,
                     const float* __restrict__ mask,
                     const float* __restrict__ obsW,
                     const float* __restrict__ attnW,
                     const float* __restrict__ recvW,
                     const float* __restrict__ recvB,
                     float* __restrict__ out)
{
    // 32 KiB, reused: phase 1 = swizzled obsW tile; phase 3 = packed hq rows
    __shared__ float lds[NS * 128];
    // per-wave folded PE weights: w_pe[e] = sum_p recvW[e][10+p]*pe[p]
    __shared__ float wpe[8 * NEMB];  // 1 KiB

    const int tid = threadIdx.x;

    // Stage S*OBS*EMB = 8192 floats into LDS (coalesced global float4 reads,
    // swizzled LDS writes). 512 threads x 4 iters x 4 floats.
#pragma unroll
    for (int k = 0; k < 4; ++k) {
        int i = (tid << 2) + (k << 11);
        float4 v = *reinterpret_cast<const float4*>(obsW + i);
        *reinterpret_cast<float4*>(&lds[obs_idx(i >> 7, (i & 127) >> 2)]) = v;
    }

    const int lane = tid & 63;
    const int wv = tid >> 6;
    const int bt = blockIdx.x * 8 + wv;   // one wave per (b,t)
    const int s = lane;                   // phase-1 role: lane = sensor

    // per-lane attnW row for phase-3 role u = lane (10 VGPRs, loaded once)
    float aW[NATTN];
    {
        const float2* ap = reinterpret_cast<const float2*>(attnW + lane * NATTN);
        float2 a0 = ap[0], a1 = ap[1], a2 = ap[2], a3 = ap[3], a4 = ap[4];
        aW[0] = a0.x; aW[1] = a0.y; aW[2] = a1.x; aW[3] = a1.y; aW[4] = a2.x;
        aW[5] = a2.y; aW[6] = a3.x; aW[7] = a3.y; aW[8] = a4.x; aW[9] = a4.y;
    }

    // positional encoding (wave-uniform; div[i] = 10^(-i/2)); native sin/cos
    const float tt = times[bt];
    const float divs[8] = {1.0f, 0.31622776601683794f, 0.1f, 0.031622776601683794f,
                           0.01f, 0.0031622776601683794f, 0.001f, 0.00031622776601683794f};
    float pe[NPE];
#pragma unroll
    for (int i = 0; i < 8; ++i) {
        float ang = tt * divs[i];
        pe[2 * i]     = __sinf(ang);
        pe[2 * i + 1] = __cosf(ang);
    }

    // c0 = recvB[10:26] . pe  (uniform; recvB via s_load)
    float c0 = 0.f;
#pragma unroll
    for (int p = 0; p < NPE; ++p) c0 += recvB[NATTN + p] * pe[p];

    // w_pe: lane e (= lane&31) folds recvW[e][10..25] with pe -> LDS strip.
    {
        const int e = lane & 31;
        const float2* rp = reinterpret_cast<const float2*>(recvW + e * ND + NATTN);
        float acc = 0.f;
#pragma unroll
        for (int p2 = 0; p2 < 8; ++p2) {
            float2 w = rp[p2];
            acc += w.x * pe[2 * p2];
            acc += w.y * pe[2 * p2 + 1];
        }
        if (lane < NEMB) wpe[wv * NEMB + e] = acc;
    }

    // per-lane inputs (coalesced: 64 lanes x 16B contiguous)
    const float4 xv = *reinterpret_cast<const float4*>(x + ((size_t)bt * NS + s) * NOBS);
    const float  mv = mask[(size_t)bt * NS + s];

    __syncthreads();  // obsW tile + wpe ready

    // hq[a] = recv_b[a] + sum_e h_e * recv_W[e][a]   (a = 0..9 only)
    // beta' = sum_e h_e * w_pe[e]
    float hq[NATTN];
#pragma unroll
    for (int a = 0; a < NATTN; ++a) hq[a] = recvB[a];  // uniform -> s_load
    float betah = 0.f;

    const float* wpb = &wpe[wv * NEMB];

#pragma unroll
    for (int eb = 0; eb < 8; ++eb) {  // e = eb*4 + j
        float a0 = 0.f, a1 = 0.f, a2 = 0.f, a3 = 0.f;
        {
            float4 w0 = *reinterpret_cast<const float4*>(&lds[obs_idx(s, 0 * 8 + eb)]);
            a0 += xv.x * w0.x; a1 += xv.x * w0.y; a2 += xv.x * w0.z; a3 += xv.x * w0.w;
            float4 w1 = *reinterpret_cast<const float4*>(&lds[obs_idx(s, 1 * 8 + eb)]);
            a0 += xv.y * w1.x; a1 += xv.y * w1.y; a2 += xv.y * w1.z; a3 += xv.y * w1.w;
            float4 w2 = *reinterpret_cast<const float4*>(&lds[obs_idx(s, 2 * 8 + eb)]);
            a0 += xv.z * w2.x; a1 += xv.z * w2.y; a2 += xv.z * w2.z; a3 += xv.z * w2.w;
            float4 w3 = *reinterpret_cast<const float4*>(&lds[obs_idx(s, 3 * 8 + eb)]);
            a0 += xv.w * w3.x; a1 += xv.w * w3.y; a2 += xv.w * w3.z; a3 += xv.w * w3.w;
        }
        const float h0 = fmaxf(a0, 0.f) * mv;
        const float h1 = fmaxf(a1, 0.f) * mv;
        const float h2 = fmaxf(a2, 0.f) * mv;
        const float h3 = fmaxf(a3, 0.f) * mv;

        // beta' contribution: uniform ds_read_b128 broadcast of 4 w_pe values
        float4 wp = *reinterpret_cast<const float4*>(wpb + eb * 4);
        betah += h0 * wp.x + h1 * wp.y + h2 * wp.z + h3 * wp.w;

        const float* rw = recvW + (eb * 4) * ND;  // uniform base -> s_load
#pragma unroll
        for (int a = 0; a < NATTN; ++a) {
            hq[a] += h0 * rw[a] + h1 * rw[ND + a] + h2 * rw[2 * ND + a] + h3 * rw[3 * ND + a];
        }
    }

    const float beta = c0 + betah;

    __syncthreads();  // all waves done READING the obsW tile -> safe to reuse

    // Stage this wave's hq rows PACKED AS F16: 6 used dwords per row,
    // 8-dword (32B) stride. Broadcast read per row becomes b128+b64 (24B)
    // instead of 3x b128 (48B): LDS pipe bytes halved.
    unsigned* hbase = reinterpret_cast<unsigned*>(&lds[0]) + wv * (NS * 8);
    {
        unsigned* hrow = hbase + s * 8;
        uint4 w0;
        w0.x = pkh(hq[0], hq[1]);
        w0.y = pkh(hq[2], hq[3]);
        w0.z = pkh(hq[4], hq[5]);
        w0.w = pkh(hq[6], hq[7]);
        uint2 w1;
        w1.x = pkh(hq[8], hq[9]);
        w1.y = pkh(beta, 0.f);
        *reinterpret_cast<uint4*>(hrow)     = w0;
        *reinterpret_cast<uint2*>(hrow + 4) = w1;
    }
    // No barrier: this wave reads only rows written by its own lanes, and
    // DS ops from one wave complete in program order.

    // Phase 3: lane = u. Per row: uniform ds_read_b128 + ds_read_b64 broadcast,
    // unpack f16 pairs, 10 FMAs vs per-lane aW, one coalesced 256B store.
    float* obase = out + (size_t)bt * (NS * NS) + lane;
#pragma unroll 4
    for (int r = 0; r < NS; ++r) {
        const unsigned* hr = hbase + r * 8;
        uint4 ha = *reinterpret_cast<const uint4*>(hr);
        uint2 hb = *reinterpret_cast<const uint2*>(hr + 4);
        float2 q01 = unpack_h2(ha.x);
        float2 q23 = unpack_h2(ha.y);
        float2 q45 = unpack_h2(ha.z);
        float2 q67 = unpack_h2(ha.w);
        float2 q89 = unpack_h2(hb.x);
        float2 qb  = unpack_h2(hb.y);
        float acc = qb.x;  // beta_r
        acc += q01.x * aW[0]; acc += q01.y * aW[1];
        acc += q23.x * aW[2]; acc += q23.y * aW[3];
        acc += q45.x * aW[4]; acc += q45.y * aW[5];
        acc += q67.x * aW[6]; acc += q67.y * aW[7];
        acc += q89.x * aW[8]; acc += q89.y * aW[9];
        obase[r * NS] = fmaxf(acc, 0.f);  // 64 lanes x 4B contiguous
    }
}

extern "C" void kernel_launch(void* const* d_in, const int* in_sizes, int n_in,
                              void* d_out, int out_size, void* d_ws, size_t ws_size,
                              hipStream_t stream) {
    const float* x     = (const float*)d_in[0];
    const float* times = (const float*)d_in[1];
    const float* mask  = (const float*)d_in[2];
    const float* obsW  = (const float*)d_in[3];
    const float* attnW = (const float*)d_in[4];
    const float* recvW = (const float*)d_in[5];
    const float* recvB = (const float*)d_in[6];
    float* out = (float*)d_out;

    // B*T = 16384 (b,t) pairs, one wave each, 8 waves per block
    raindrop_kernel<<<dim3((NB * NT) / 8), dim3(512), 0, stream>>>(
        x, times, mask, obsW, attnW, recvW, recvB, out);
}

// Round 8
// 65.849 us; speedup vs baseline: 1.3118x; 1.2673x over previous
//
#include <hip/hip_runtime.h>
#include <math.h>

#define NB 32
#define NT 512
#define NS 64
#define NOBS 4
#define NEMB 32
#define NPE 16
#define NATTN 10
#define ND 26  // ATTN + PE

// obs_emb_weights LDS layout: 64 rows (sensor s) x 128 dwords (o*32+e),
// 16B-chunk XOR swizzle so per-lane ds_read_b128 of row s spreads banks.
__device__ __forceinline__ int obs_idx(int s, int chunk) {
    return (s << 7) + (((chunk ^ (s & 7)) & 31) << 2);
}

__global__ __launch_bounds__(512)
void raindrop_kernel(const float* __restrict__ x,
                     const float* __restrict__ times,
                     const float* __restrict__ mask,
                     const float* __restrict__ obsW,
                     const float* __restrict__ attnW,
                     const float* __restrict__ recvW,
                     const float* __restrict__ recvB,
                     float* __restrict__ out)
{
    // 32 KiB, reused: phase 1 = swizzled obsW tile; phase 3 = hq rows
    __shared__ float lds[NS * 128];
    // per-wave folded PE weights: w_pe[e] = sum_p recvW[e][10+p]*pe[p]
    __shared__ float wpe[8 * NEMB];  // 1 KiB

    const int tid = threadIdx.x;

    // Stage S*OBS*EMB = 8192 floats into LDS (coalesced global float4 reads,
    // swizzled LDS writes). 512 threads x 4 iters x 4 floats.
#pragma unroll
    for (int k = 0; k < 4; ++k) {
        int i = (tid << 2) + (k << 11);
        float4 v = *reinterpret_cast<const float4*>(obsW + i);
        *reinterpret_cast<float4*>(&lds[obs_idx(i >> 7, (i & 127) >> 2)]) = v;
    }

    const int lane = tid & 63;
    const int wv = tid >> 6;
    const int bt = blockIdx.x * 8 + wv;   // one wave per (b,t)
    const int s = lane;                   // phase-1 role: lane = sensor

    // positional encoding (wave-uniform; div[i] = 10^(-i/2)); native sin/cos
    const float tt = times[bt];
    const float divs[8] = {1.0f, 0.31622776601683794f, 0.1f, 0.031622776601683794f,
                           0.01f, 0.0031622776601683794f, 0.001f, 0.00031622776601683794f};
    float pe[NPE];
#pragma unroll
    for (int i = 0; i < 8; ++i) {
        float ang = tt * divs[i];
        pe[2 * i]     = __sinf(ang);
        pe[2 * i + 1] = __cosf(ang);
    }

    // c0 = recvB[10:26] . pe  (uniform; recvB via s_load)
    float c0 = 0.f;
#pragma unroll
    for (int p = 0; p < NPE; ++p) c0 += recvB[NATTN + p] * pe[p];

    // w_pe: lane e (= lane&31) folds recvW[e][10..25] with pe -> LDS strip.
    {
        const int e = lane & 31;
        const float2* rp = reinterpret_cast<const float2*>(recvW + e * ND + NATTN);
        float acc = 0.f;
#pragma unroll
        for (int p2 = 0; p2 < 8; ++p2) {
            float2 w = rp[p2];
            acc += w.x * pe[2 * p2];
            acc += w.y * pe[2 * p2 + 1];
        }
        if (lane < NEMB) wpe[wv * NEMB + e] = acc;
    }

    // per-lane inputs (coalesced: 64 lanes x 16B contiguous)
    const float4 xv = *reinterpret_cast<const float4*>(x + ((size_t)bt * NS + s) * NOBS);
    const float  mv = mask[(size_t)bt * NS + s];

    __syncthreads();  // obsW tile + wpe ready

    // hq[a] = recv_b[a] + sum_e h_e * recv_W[e][a]   (a = 0..9 only)
    // beta' = sum_e h_e * w_pe[e]
    float hq[NATTN];
#pragma unroll
    for (int a = 0; a < NATTN; ++a) hq[a] = recvB[a];  // uniform -> s_load
    float betah = 0.f;

    const float* wpb = &wpe[wv * NEMB];

#pragma unroll
    for (int eb = 0; eb < 8; ++eb) {  // e = eb*4 + j
        float a0 = 0.f, a1 = 0.f, a2 = 0.f, a3 = 0.f;
        {
            float4 w0 = *reinterpret_cast<const float4*>(&lds[obs_idx(s, 0 * 8 + eb)]);
            a0 += xv.x * w0.x; a1 += xv.x * w0.y; a2 += xv.x * w0.z; a3 += xv.x * w0.w;
            float4 w1 = *reinterpret_cast<const float4*>(&lds[obs_idx(s, 1 * 8 + eb)]);
            a0 += xv.y * w1.x; a1 += xv.y * w1.y; a2 += xv.y * w1.z; a3 += xv.y * w1.w;
            float4 w2 = *reinterpret_cast<const float4*>(&lds[obs_idx(s, 2 * 8 + eb)]);
            a0 += xv.z * w2.x; a1 += xv.z * w2.y; a2 += xv.z * w2.z; a3 += xv.z * w2.w;
            float4 w3 = *reinterpret_cast<const float4*>(&lds[obs_idx(s, 3 * 8 + eb)]);
            a0 += xv.w * w3.x; a1 += xv.w * w3.y; a2 += xv.w * w3.z; a3 += xv.w * w3.w;
        }
        const float h0 = fmaxf(a0, 0.f) * mv;
        const float h1 = fmaxf(a1, 0.f) * mv;
        const float h2 = fmaxf(a2, 0.f) * mv;
        const float h3 = fmaxf(a3, 0.f) * mv;

        // beta' contribution: uniform ds_read_b128 broadcast of 4 w_pe values
        float4 wp = *reinterpret_cast<const float4*>(wpb + eb * 4);
        betah += h0 * wp.x + h1 * wp.y + h2 * wp.z + h3 * wp.w;

        const float* rw = recvW + (eb * 4) * ND;  // uniform base -> s_load
#pragma unroll
        for (int a = 0; a < NATTN; ++a) {
            hq[a] += h0 * rw[a] + h1 * rw[ND + a] + h2 * rw[2 * ND + a] + h3 * rw[3 * ND + a];
        }
    }

    const float beta = c0 + betah;

    __syncthreads();  // all waves done READING the obsW tile -> safe to reuse

    // Stage this wave's hq rows (wave-private region, 64 rows x 12 floats).
    float* hbase = &lds[wv * (NS * 12)];
    {
        float* hrow = hbase + s * 12;
        float4 v0 = {hq[0], hq[1], hq[2], hq[3]};
        float4 v1 = {hq[4], hq[5], hq[6], hq[7]};
        float4 v2 = {hq[8], hq[9], beta, 0.f};
        *reinterpret_cast<float4*>(hrow)     = v0;
        *reinterpret_cast<float4*>(hrow + 4) = v1;
        *reinterpret_cast<float4*>(hrow + 8) = v2;
    }
    // No barrier: this wave reads only rows its own lanes wrote, and DS ops
    // from one wave complete in program order.

    // Phase 3: wave = 4 row-groups x 16 lanes. Group g = lane>>4 processes
    // row r+g; lane i = lane&15 owns u-quad 4i..4i+3 (attnW in 40 VGPRs).
    // Per iter: 3 ds_read_b128 at 4 distinct group addrs (rows 48B apart ->
    // disjoint bank quads, broadcast within group, conflict-free) + 40 FMA
    // + one coalesced 1KB wave store (4 rows x 256B).
    const int g = lane >> 4;
    const int iu = lane & 15;

    float aw0[NATTN], aw1[NATTN], aw2[NATTN], aw3[NATTN];
    {
        const float2* ap = reinterpret_cast<const float2*>(attnW + (iu * 4) * NATTN);
#pragma unroll
        for (int q = 0; q < 5; ++q) {
            float2 v0 = ap[q];      aw0[2*q] = v0.x; aw0[2*q+1] = v0.y;
            float2 v1 = ap[5 + q];  aw1[2*q] = v1.x; aw1[2*q+1] = v1.y;
            float2 v2 = ap[10 + q]; aw2[2*q] = v2.x; aw2[2*q+1] = v2.y;
            float2 v3 = ap[15 + q]; aw3[2*q] = v3.x; aw3[2*q+1] = v3.y;
        }
    }

    const float* hgbase = hbase + g * 12;                 // row r+g
    float* optr = out + (size_t)bt * (NS * NS) + g * NS + iu * 4;
#pragma unroll 4
    for (int r = 0; r < NS; r += 4) {
        const float* hr = hgbase + r * 12;
        float4 h0 = *reinterpret_cast<const float4*>(hr);
        float4 h1 = *reinterpret_cast<const float4*>(hr + 4);
        float4 h2 = *reinterpret_cast<const float4*>(hr + 8);
        float acc0 = h2.z, acc1 = h2.z, acc2 = h2.z, acc3 = h2.z;  // beta_r
        acc0 += h0.x * aw0[0]; acc1 += h0.x * aw1[0]; acc2 += h0.x * aw2[0]; acc3 += h0.x * aw3[0];
        acc0 += h0.y * aw0[1]; acc1 += h0.y * aw1[1]; acc2 += h0.y * aw2[1]; acc3 += h0.y * aw3[1];
        acc0 += h0.z * aw0[2]; acc1 += h0.z * aw1[2]; acc2 += h0.z * aw2[2]; acc3 += h0.z * aw3[2];
        acc0 += h0.w * aw0[3]; acc1 += h0.w * aw1[3]; acc2 += h0.w * aw2[3]; acc3 += h0.w * aw3[3];
        acc0 += h1.x * aw0[4]; acc1 += h1.x * aw1[4]; acc2 += h1.x * aw2[4]; acc3 += h1.x * aw3[4];
        acc0 += h1.y * aw0[5]; acc1 += h1.y * aw1[5]; acc2 += h1.y * aw2[5]; acc3 += h1.y * aw3[5];
        acc0 += h1.z * aw0[6]; acc1 += h1.z * aw1[6]; acc2 += h1.z * aw2[6]; acc3 += h1.z * aw3[6];
        acc0 += h1.w * aw0[7]; acc1 += h1.w * aw1[7]; acc2 += h1.w * aw2[7]; acc3 += h1.w * aw3[7];
        acc0 += h2.x * aw0[8]; acc1 += h2.x * aw1[8]; acc2 += h2.x * aw2[8]; acc3 += h2.x * aw3[8];
        acc0 += h2.y * aw0[9]; acc1 += h2.y * aw1[9]; acc2 += h2.y * aw2[9]; acc3 += h2.y * aw3[9];
        float4 rv;
        rv.x = fmaxf(acc0, 0.f);
        rv.y = fmaxf(acc1, 0.f);
        rv.z = fmaxf(acc2, 0.f);
        rv.w = fmaxf(acc3, 0.f);
        *reinterpret_cast<float4*>(optr) = rv;
        optr += 4 * NS;
    }
}

extern "C" void kernel_launch(void* const* d_in, const int* in_sizes, int n_in,
                              void* d_out, int out_size, void* d_ws, size_t ws_size,
                              hipStream_t stream) {
    const float* x     = (const float*)d_in[0];
    const float* times = (const float*)d_in[1];
    const float* mask  = (const float*)d_in[2];
    const float* obsW  = (const float*)d_in[3];
    const float* attnW = (const float*)d_in[4];
    const float* recvW = (const float*)d_in[5];
    const float* recvB = (const float*)d_in[6];
    float* out = (float*)d_out;

    // B*T = 16384 (b,t) pairs, one wave each, 8 waves per block
    raindrop_kernel<<<dim3((NB * NT) / 8), dim3(512), 0, stream>>>(
        x, times, mask, obsW, attnW, recvW, recvB, out);
}